// Round 2
// baseline (2181.278 us; speedup 1.0000x reference)
//
#include <hip/hip_runtime.h>
#include <hip/hip_bf16.h>
#include <math.h>

#define NREVS 1024
#define NASP  20
#define FDIM  256
#define LSEQ  256
#define NCC   100
#define IMD   868
#define NB    128

using f32x4  = __attribute__((ext_vector_type(4))) float;
using fl4    = __attribute__((ext_vector_type(4))) float;
using bf16x8 = __attribute__((ext_vector_type(8))) short;
using s16x4  = __attribute__((ext_vector_type(4))) short;

__device__ __forceinline__ unsigned short f2bf(float f) {
    unsigned int u = __float_as_uint(f);
    u = (u + 0x7FFFu + ((u >> 16) & 1u)) >> 16;
    return (unsigned short)u;
}
__device__ __forceinline__ float bf2f(unsigned short s) {
    return __uint_as_float(((unsigned int)s) << 16);
}
__device__ __forceinline__ s16x4 pack4(fl4 v) {
    s16x4 r;
    r[0] = (short)f2bf(v[0]); r[1] = (short)f2bf(v[1]);
    r[2] = (short)f2bf(v[2]); r[3] = (short)f2bf(v[3]);
    return r;
}

// ---- static device scratch ----
__device__ unsigned short g_uh[2][NREVS*LSEQ*FDIM];   // relu(X@W+b), bf16 (hi)
__device__ unsigned short g_WT[2][256*256];           // W^T bf16 hi [f][k]
__device__ unsigned short g_WTlo[2][256*256];         // W^T bf16 lo [f][k]
__device__ unsigned short g_KT[2][112*768];           // conv w bf16 [c(pad112)][kh*256+f]
__device__ float g_cex[2][NASP];                      // emb_asp[a]·w_attn[256:]
__device__ float g_hrow[2][NREVS*LSEQ];               // sum_f h  (fp32-exact)
__device__ float g_hw  [2][NREVS*LSEQ];               // sum_f h*w_ex[f]
__device__ float g_ssum[2][NREVS*FDIM];               // sum_l h
__device__ float g_scnt[2][NREVS*FDIM];               // count_l h!=0
__device__ unsigned int g_smax[2][NREVS*FDIM];        // max_l h (uint-punned, h>=0)
__device__ float g_r  [2][NREVS*NASP*FDIM];
__device__ float g_x  [2][NREVS*IMD];                 // [clsr|avg|mx|cnn]
__device__ float g_sex[2][NREVS*NASP];
__device__ float g_sim[2][NREVS];
__device__ float g_ex [2][NB*NASP*FDIM];
__device__ float g_im [2][NB*IMD];
__device__ float g_exh[NB*NASP*FDIM];
__device__ float g_imh[NB*FDIM];

// ================= prep: weight casts / transposes / zero-init =================
__global__ __launch_bounds__(256) void k_prep(
    const float* __restrict__ Wub, const float* __restrict__ Wib,
    const float* __restrict__ Ku,  const float* __restrict__ Ki,
    const float* __restrict__ embu, const float* __restrict__ embi,
    const float* __restrict__ wexu, const float* __restrict__ wexi)
{
    int b = blockIdx.x, t = threadIdx.x;
    if (b < 64) {                       // W^T hi, 32 blocks per side
        int side = b >> 5;
        const float* W = side ? Wib : Wub;
        unsigned short* o = g_WT[side];
        int idx = (b & 31) * 2048 + t * 8;   // [f][k]
        int f = idx >> 8, k0 = idx & 255;
        s16x4 p0, p1;
        #pragma unroll
        for (int j = 0; j < 4; j++) p0[j] = (short)f2bf(W[(k0+j)*256 + f]);
        #pragma unroll
        for (int j = 0; j < 4; j++) p1[j] = (short)f2bf(W[(k0+4+j)*256 + f]);
        *(s16x4*)&o[idx]   = p0;
        *(s16x4*)&o[idx+4] = p1;
    } else if (b < 128) {               // W^T lo
        int bb = b - 64;
        int side = bb >> 5;
        const float* W = side ? Wib : Wub;
        unsigned short* o = g_WTlo[side];
        int idx = (bb & 31) * 2048 + t * 8;
        int f = idx >> 8, k0 = idx & 255;
        s16x4 p0, p1;
        #pragma unroll
        for (int j = 0; j < 4; j++) {
            float v = W[(k0+j)*256 + f];
            unsigned short h = f2bf(v);
            p0[j] = (short)f2bf(v - bf2f(h));
        }
        #pragma unroll
        for (int j = 0; j < 4; j++) {
            float v = W[(k0+4+j)*256 + f];
            unsigned short h = f2bf(v);
            p1[j] = (short)f2bf(v - bf2f(h));
        }
        *(s16x4*)&o[idx]   = p0;
        *(s16x4*)&o[idx+4] = p1;
    } else if (b < 212) {               // conv weights, 42 blocks per side
        int bb = b - 128;
        int side = bb / 42; bb -= side * 42;
        const float* K = side ? Ki : Ku;
        unsigned short* o = g_KT[side];
        int idx = bb * 2048 + t * 8;
        int c = idx / 768;
        if (c < NCC) {
            fl4 v0 = *(const fl4*)&K[idx];
            fl4 v1 = *(const fl4*)&K[idx+4];
            *(s16x4*)&o[idx]   = pack4(v0);
            *(s16x4*)&o[idx+4] = pack4(v1);
        } else {
            s16x4 z = {0,0,0,0};
            *(s16x4*)&o[idx] = z; *(s16x4*)&o[idx+4] = z;
        }
    } else if (b == 212) {
        if (t < 40) {
            int side = t / 20, a = t - side*20;
            const float* e = side ? embi : embu;
            const float* w = side ? wexi : wexu;
            float s = 0.f;
            for (int f = 0; f < 256; f++) s += e[a*256+f] * w[256+f];
            g_cex[side][a] = s;
        }
    } else {                            // zero accumulators: 5 arrays x 512 blocks
        int zb = b - 213;
        int arr = zb >> 9;
        int idx = (zb & 511) * 1024 + t * 4;
        float* p;
        if (arr == 0) p = &g_hrow[0][0];
        else if (arr == 1) p = &g_hw[0][0];
        else if (arr == 2) p = &g_ssum[0][0];
        else if (arr == 3) p = &g_scnt[0][0];
        else p = (float*)&g_smax[0][0];
        fl4 z = {0.f,0.f,0.f,0.f};
        *(fl4*)&p[idx] = z;
    }
}

// ================= K1: uh = relu(X @ W + b), split-bf16 3-product =================
// Block: 128 l-rows x 128 f (f-half). D[f][l] accumulated over 3 products.
// Epilogue: store bf16 uh; exact fp32 reductions hrow/hw (per l) and stats (per f).
__global__ __launch_bounds__(256) void k1_gemm(int side,
    const float* __restrict__ X, const float* __restrict__ bias,
    const float* __restrict__ wex)
{
    __shared__ unsigned short WThi[128*264];   // 67584 B
    __shared__ unsigned short WTlo[128*264];   // 67584 B
    __shared__ unsigned short Xhi[128*40];     // 10240 B
    __shared__ unsigned short Xlo[128*40];     // 10240 B
    const unsigned short* WTg  = g_WT[side];
    const unsigned short* WTlg = g_WTlo[side];
    unsigned short* out = g_uh[side];
    int bx = blockIdx.x;
    int lb = bx >> 1, fh = bx & 1;
    int row0 = lb * 128, f0 = fh * 128;
    int n = bx >> 2;                           // review index
    int t = threadIdx.x;
    int lane = t & 63, w = t >> 6;
    int g = lane >> 4, ln = lane & 15;
    int wf = w >> 1, wl = w & 1;

    #pragma unroll
    for (int i = 0; i < 16; i++) {             // stage W hi+lo [128 f][256 k]
        int idx = i*2048 + t*8;
        int f = idx >> 8, k = idx & 255;
        bf16x8 vh = *(const bf16x8*)&WTg [(f0+f)*256 + k];
        bf16x8 vl = *(const bf16x8*)&WTlg[(f0+f)*256 + k];
        *(bf16x8*)&WThi[f*264 + k] = vh;
        *(bf16x8*)&WTlo[f*264 + k] = vl;
    }

    f32x4 zf = {0.f,0.f,0.f,0.f};
    f32x4 acc[4][4];
    #pragma unroll
    for (int i = 0; i < 4; i++)
        #pragma unroll
        for (int j = 0; j < 4; j++) acc[i][j] = zf;

    for (int s = 0; s < 8; s++) {
        #pragma unroll
        for (int i = 0; i < 4; i++) {          // stage X slice [128 l][32 k] hi+lo
            int idx = i*1024 + t*4;
            int r = idx >> 5, kk = idx & 31;
            fl4 v = *(const fl4*)&X[(long)(row0 + r)*256 + s*32 + kk];
            s16x4 ph, pl;
            #pragma unroll
            for (int j = 0; j < 4; j++) {
                unsigned short h = f2bf(v[j]);
                ph[j] = (short)h;
                pl[j] = (short)f2bf(v[j] - bf2f(h));
            }
            *(s16x4*)&Xhi[r*40 + kk] = ph;
            *(s16x4*)&Xlo[r*40 + kk] = pl;
        }
        __syncthreads();
        bf16x8 ah[4], al[4], bh[4], bl[4];
        #pragma unroll
        for (int ft = 0; ft < 4; ft++) {
            int fr = (wf*64 + ft*16 + ln)*264 + s*32 + g*8;
            ah[ft] = *(const bf16x8*)&WThi[fr];
            al[ft] = *(const bf16x8*)&WTlo[fr];
        }
        #pragma unroll
        for (int lt = 0; lt < 4; lt++) {
            int lr = (wl*64 + lt*16 + ln)*40 + g*8;
            bh[lt] = *(const bf16x8*)&Xhi[lr];
            bl[lt] = *(const bf16x8*)&Xlo[lr];
        }
        #pragma unroll
        for (int ft = 0; ft < 4; ft++)
            #pragma unroll
            for (int lt = 0; lt < 4; lt++) {
                acc[ft][lt] = __builtin_amdgcn_mfma_f32_16x16x32_bf16(ah[ft], bh[lt], acc[ft][lt], 0, 0, 0);
                acc[ft][lt] = __builtin_amdgcn_mfma_f32_16x16x32_bf16(al[ft], bh[lt], acc[ft][lt], 0, 0, 0);
                acc[ft][lt] = __builtin_amdgcn_mfma_f32_16x16x32_bf16(ah[ft], bl[lt], acc[ft][lt], 0, 0, 0);
            }
        __syncthreads();
    }

    // ---- epilogue: bias+relu, bf16 store, exact reductions ----
    float bv[4][4], wv[4][4];
    #pragma unroll
    for (int ft = 0; ft < 4; ft++) {
        int fb = f0 + wf*64 + ft*16 + g*4;
        fl4 b4 = *(const fl4*)&bias[fb];
        fl4 w4 = *(const fl4*)&wex[fb];
        #pragma unroll
        for (int r = 0; r < 4; r++) { bv[ft][r] = b4[r]; wv[ft][r] = w4[r]; }
    }
    float hs_l[4] = {0.f,0.f,0.f,0.f};
    float hw_l[4] = {0.f,0.f,0.f,0.f};
    float fsum[4][4], fmx[4][4], fcnt[4][4];
    #pragma unroll
    for (int ft = 0; ft < 4; ft++)
        #pragma unroll
        for (int r = 0; r < 4; r++) { fsum[ft][r]=0.f; fmx[ft][r]=0.f; fcnt[ft][r]=0.f; }

    #pragma unroll
    for (int ft = 0; ft < 4; ft++) {
        int fb = f0 + wf*64 + ft*16 + g*4;
        #pragma unroll
        for (int lt = 0; lt < 4; lt++) {
            int row = row0 + wl*64 + lt*16 + ln;
            s16x4 pk;
            #pragma unroll
            for (int r = 0; r < 4; r++) {
                float h = fmaxf(acc[ft][lt][r] + bv[ft][r], 0.f);
                pk[r] = (short)f2bf(h);
                hs_l[lt] += h;
                hw_l[lt] += h * wv[ft][r];
                fsum[ft][r] += h;
                fmx[ft][r] = fmaxf(fmx[ft][r], h);
                fcnt[ft][r] += (h != 0.f) ? 1.f : 0.f;
            }
            *(s16x4*)&out[(long)row*256 + fb] = pk;
        }
    }

    // hrow/hw: reduce over g (f-dim within wave), then wf via LDS, atomic over f-halves
    float* red = (float*)Xhi;                  // 512 floats needed, 20KB available
    #pragma unroll
    for (int lt = 0; lt < 4; lt++) {
        float hs = hs_l[lt], hw2 = hw_l[lt];
        hs += __shfl_xor(hs, 16);  hs += __shfl_xor(hs, 32);
        hw2 += __shfl_xor(hw2, 16); hw2 += __shfl_xor(hw2, 32);
        if (g == 0) {
            int lidx = wl*64 + lt*16 + ln;
            red[wf*128 + lidx] = hs;
            red[256 + wf*128 + lidx] = hw2;
        }
    }
    __syncthreads();
    if (t < 128) {
        float hs = red[t] + red[128+t];
        float hw2 = red[256+t] + red[384+t];
        atomicAdd(&g_hrow[side][row0 + t], hs);
        atomicAdd(&g_hw[side][row0 + t], hw2);
    }

    // stats: reduce over ln (l-dim), atomic over wl-waves and l-blocks
    #pragma unroll
    for (int ft = 0; ft < 4; ft++)
        #pragma unroll
        for (int r = 0; r < 4; r++) {
            float s = fsum[ft][r], c = fcnt[ft][r], m = fmx[ft][r];
            #pragma unroll
            for (int o = 1; o < 16; o <<= 1) {
                s += __shfl_xor(s, o);
                c += __shfl_xor(c, o);
                m = fmaxf(m, __shfl_xor(m, o));
            }
            if (ln == 0) {
                int f = f0 + wf*64 + ft*16 + g*4 + r;
                atomicAdd(&g_ssum[side][n*256 + f], s);
                atomicAdd(&g_scnt[side][n*256 + f], c);
                atomicMax(&g_smax[side][n*256 + f], __float_as_uint(m));
            }
        }
}

// ================= K2: per-review mega kernel (conv + aspects) =================
__device__ __forceinline__ void stage_kt(const unsigned short* __restrict__ KT,
                                         unsigned short* __restrict__ dst, int kk, int t)
{
    {
        int c = t >> 2, j8 = (t & 3) * 8;
        bf16x8 v = *(const bf16x8*)&KT[c*768 + kk + j8];
        *(bf16x8*)&dst[c*40 + j8] = v;
    }
    if (t < 192) {
        int i2 = t + 256;
        int c = i2 >> 2, j8 = (i2 & 3) * 8;
        bf16x8 v = *(const bf16x8*)&KT[c*768 + kk + j8];
        *(bf16x8*)&dst[c*40 + j8] = v;
    }
}

__global__ __launch_bounds__(256) void k2_mega(int side,
    const float* __restrict__ bk, const float* __restrict__ loc)
{
    __shared__ unsigned short uhs[258*264];
    __shared__ unsigned short kbuf[2][112*40];
    __shared__ float redbuf[4*112];
    const unsigned short* uh = g_uh[side];
    const unsigned short* KT = g_KT[side];
    float* rout = g_r[side];
    float* xout = g_x[side];
    int n = blockIdx.x;
    int t = threadIdx.x, lane = t & 63, w = t >> 6;
    int g = lane >> 4, ln = lane & 15;

    // phase 0: uh[n] -> LDS
    const unsigned short* src = uh + (long)n * (LSEQ*FDIM);
    #pragma unroll
    for (int i = 0; i < 32; i++) {
        int idx = i*2048 + t*8;
        int r = idx >> 8, c = idx & 255;
        bf16x8 v = *(const bf16x8*)&src[idx];
        *(bf16x8*)&uhs[r*264 + c] = v;
    }
    if (t < 132) {
        s16x4 z = {0,0,0,0};
        *(s16x4*)&uhs[256*264 + t*4] = z;
    }
    stage_kt(KT, kbuf[0], 0, t);
    __syncthreads();

    // phase 1: conv as windowed GEMM, fused max over l
    f32x4 zf = {0.f,0.f,0.f,0.f};
    f32x4 acc[4][7];
    #pragma unroll
    for (int i = 0; i < 4; i++)
        #pragma unroll
        for (int j = 0; j < 7; j++) acc[i][j] = zf;
    int l0 = w * 64;
    for (int s = 0; s < 24; s++) {
        if (s + 1 < 24) stage_kt(KT, kbuf[(s+1)&1], (s+1)*32, t);
        int kk = s * 32;
        int kh = kk >> 8, fo = kk & 255;
        const unsigned short* kb = kbuf[s&1];
        bf16x8 af[4];
        #pragma unroll
        for (int mt = 0; mt < 4; mt++)
            af[mt] = *(const bf16x8*)&uhs[(l0 + mt*16 + ln + kh)*264 + fo + g*8];
        #pragma unroll
        for (int nt = 0; nt < 7; nt++) {
            bf16x8 bfr = *(const bf16x8*)&kb[(nt*16 + ln)*40 + g*8];
            #pragma unroll
            for (int mt = 0; mt < 4; mt++)
                acc[mt][nt] = __builtin_amdgcn_mfma_f32_16x16x32_bf16(af[mt], bfr, acc[mt][nt], 0, 0, 0);
        }
        __syncthreads();
    }
    #pragma unroll
    for (int nt = 0; nt < 7; nt++) {
        float m = -1e30f;
        #pragma unroll
        for (int mt = 0; mt < 4; mt++)
            #pragma unroll
            for (int r = 0; r < 4; r++) {
                int lp = l0 + mt*16 + g*4 + r;
                if (lp < 254) m = fmaxf(m, acc[mt][nt][r]);
            }
        m = fmaxf(m, __shfl_xor(m, 16));
        m = fmaxf(m, __shfl_xor(m, 32));
        if (lane < 16) redbuf[w*112 + nt*16 + ln] = m;
    }
    __syncthreads();
    if (t < NCC) {
        float m = fmaxf(fmaxf(redbuf[t], redbuf[112+t]),
                        fmaxf(redbuf[224+t], redbuf[336+t]));
        xout[(long)n*IMD + 768 + t] = fmaxf(m + bk[t], 0.f);
    }

    // phase 2: aspects r = loc @ uh
    unsigned short* locs = &kbuf[0][0];
    #pragma unroll
    for (int i = 0; i < 3; i++) {
        int idx = i*256 + t;
        if (idx < 640) {
            int r = idx >> 5, c = (idx & 31) * 8;
            fl4 v0 = *(const fl4*)&loc[((long)n*NASP + r)*256 + c];
            fl4 v1 = *(const fl4*)&loc[((long)n*NASP + r)*256 + c + 4];
            *(s16x4*)&locs[r*264 + c]     = pack4(v0);
            *(s16x4*)&locs[r*264 + c + 4] = pack4(v1);
        }
    }
    {
        s16x4 z = {0,0,0,0};
        #pragma unroll
        for (int i = 0; i < 3; i++) {
            int idx = i*256 + t;
            int r = 20 + (idx >> 6), c = (idx & 63) * 4;
            *(s16x4*)&locs[r*264 + c] = z;
        }
    }
    __syncthreads();

    f32x4 acc2[2][4];
    #pragma unroll
    for (int i = 0; i < 2; i++)
        #pragma unroll
        for (int j = 0; j < 4; j++) acc2[i][j] = zf;
    int f0w = w * 64;
    for (int ks = 0; ks < 8; ks++) {
        int k0 = ks * 32;
        bf16x8 af2[2];
        #pragma unroll
        for (int mt = 0; mt < 2; mt++)
            af2[mt] = *(const bf16x8*)&locs[(mt*16 + ln)*264 + k0 + g*8];
        #pragma unroll
        for (int nt = 0; nt < 4; nt++) {
            int f = f0w + nt*16 + ln;
            int kb2 = k0 + g*8;
            bf16x8 bfr;
            #pragma unroll
            for (int j = 0; j < 8; j++)
                bfr[j] = (short)uhs[(kb2 + j)*264 + f];
            #pragma unroll
            for (int mt = 0; mt < 2; mt++)
                acc2[mt][nt] = __builtin_amdgcn_mfma_f32_16x16x32_bf16(af2[mt], bfr, acc2[mt][nt], 0, 0, 0);
        }
    }
    #pragma unroll
    for (int mt = 0; mt < 2; mt++)
        #pragma unroll
        for (int nt = 0; nt < 4; nt++)
            #pragma unroll
            for (int r = 0; r < 4; r++) {
                int a = mt*16 + g*4 + r;
                if (a < NASP) {
                    int f = f0w + nt*16 + ln;
                    rout[((long)n*NASP + a)*256 + f] = acc2[mt][nt][r];
                }
            }
}

// ================= small fp32 GEMM (cls / ex_h / im_h) =================
__global__ __launch_bounds__(256) void k_small_gemm(int mode,
    const float* __restrict__ extA, const float* __restrict__ Bm,
    const float* __restrict__ bias, int K1, int K2)
{
    __shared__ float As[16*1736];
    const float *A1, *A2 = nullptr;
    float* Cout; int ldc;
    if (mode == 0)      { A1 = extA;    Cout = g_x[0]; ldc = IMD; }
    else if (mode == 1) { A1 = extA;    Cout = g_x[1]; ldc = IMD; }
    else if (mode == 2) { A1 = g_ex[0]; A2 = g_ex[1]; Cout = g_exh; ldc = 256; }
    else                { A1 = g_im[0]; A2 = g_im[1]; Cout = g_imh; ldc = 256; }
    int K = K1 + K2;
    int t = threadIdx.x;
    int m0 = blockIdx.x * 16;
    for (int i = t; i < 16*K1; i += 256) {
        int m = i / K1, k = i - m*K1;
        As[m*K + k] = A1[(long)(m0+m)*K1 + k];
    }
    if (K2 > 0)
        for (int i = t; i < 16*K2; i += 256) {
            int m = i / K2, k = i - m*K2;
            As[m*K + K1 + k] = A2[(long)(m0+m)*K2 + k];
        }
    __syncthreads();
    float accv[16];
    #pragma unroll
    for (int m = 0; m < 16; m++) accv[m] = 0.f;
    for (int k = 0; k < K; k += 4) {
        float bv0 = Bm[(k+0)*256 + t];
        float bv1 = Bm[(k+1)*256 + t];
        float bv2 = Bm[(k+2)*256 + t];
        float bv3 = Bm[(k+3)*256 + t];
        #pragma unroll
        for (int m = 0; m < 16; m++) {
            fl4 a = *(const fl4*)&As[m*K + k];
            accv[m] += a[0]*bv0 + a[1]*bv1 + a[2]*bv2 + a[3]*bv3;
        }
    }
    float bb = bias ? bias[t] : 0.f;
    #pragma unroll
    for (int m = 0; m < 16; m++)
        Cout[(long)(m0+m)*ldc + t] = fmaxf(accv[m] + bb, 0.f);
}

// ================= K3: stats finalize + attention scores (exact via hrow/hw) ====
__global__ __launch_bounds__(256) void k3_scores(int side,
    const float* __restrict__ loc, const float* __restrict__ wim)
{
    __shared__ float shr[256], shw[256], sb[256];
    const float* cex  = g_cex[side];
    float* xout = g_x[side];
    float* sex = g_sex[side];
    float* sim = g_sim[side];
    int n = blockIdx.x, t = threadIdx.x, lane = t & 63, w = t >> 6;

    {   // finalize avg/mx into x; stage hrow/hw
        float ssum = g_ssum[side][n*256 + t];
        float scnt = g_scnt[side][n*256 + t];
        float smax = __uint_as_float(g_smax[side][n*256 + t]);
        xout[(long)n*IMD + 256 + t] = ssum / scnt;
        xout[(long)n*IMD + 512 + t] = smax;
        shr[t] = g_hrow[side][n*256 + t];
        shw[t] = g_hw[side][n*256 + t];
    }
    __syncthreads();

    #pragma unroll
    for (int ai = 0; ai < 5; ai++) {
        int a = w*5 + ai;
        fl4 lv = *(const fl4*)&loc[((long)n*NASP + a)*256 + lane*4];
        float s2 = lv[0]*shr[lane*4]   + lv[1]*shr[lane*4+1]
                 + lv[2]*shr[lane*4+2] + lv[3]*shr[lane*4+3];
        float dr = lv[0]*shw[lane*4]   + lv[1]*shw[lane*4+1]
                 + lv[2]*shw[lane*4+2] + lv[3]*shw[lane*4+3];
        #pragma unroll
        for (int o = 1; o < 64; o <<= 1) {
            s2 += __shfl_xor(s2, o);
            dr += __shfl_xor(dr, o);
        }
        if (lane == 0) sex[n*NASP + a] = tanhf(s2 * (dr + cex[a]));
    }
    float p = 0.f;
    for (int j = t; j < IMD; j += 256) p += xout[(long)n*IMD + j] * wim[j];
    sb[t] = p;
    __syncthreads();
    if (t < 32) {
        float q = sb[t] + sb[t+32] + sb[t+64] + sb[t+96]
                + sb[t+128] + sb[t+160] + sb[t+192] + sb[t+224];
        #pragma unroll
        for (int o = 1; o < 32; o <<= 1) q += __shfl_xor(q, o);
        if (t == 0) sim[n] = tanhf(q);
    }
}

// ================= K4: segment softmax + weighted segment sums =================
__global__ __launch_bounds__(256) void k4_seg(int side, const int* __restrict__ seg)
{
    __shared__ int sred[256];
    __shared__ int sse[2];
    const float* sex = g_sex[side];
    const float* sim = g_sim[side];
    const float* rbuf = g_r[side];
    const float* xbuf = g_x[side];
    float* exout = g_ex[side];
    float* imout = g_im[side];
    int b = blockIdx.x, t = threadIdx.x;
    int clt = 0, cle = 0;
    #pragma unroll
    for (int i = 0; i < 4; i++) {
        int v = seg[i*256 + t];
        clt += (v < b); cle += (v <= b);
    }
    sred[t] = clt | (cle << 11);
    __syncthreads();
    if (t < 64) {
        int q = sred[t] + sred[t+64] + sred[t+128] + sred[t+192];
        #pragma unroll
        for (int o = 1; o < 64; o <<= 1) q += __shfl_xor(q, o);
        if (t == 0) { sse[0] = q & 2047; sse[1] = (q >> 11) & 2047; }
    }
    __syncthreads();
    int start = sse[0], end = sse[1];

    for (int a = 0; a < NASP; a++) {
        float m = -1e30f;
        for (int i = start; i < end; i++) m = fmaxf(m, sex[i*NASP + a]);
        float z = 0.f;
        for (int i = start; i < end; i++) z += expf(sex[i*NASP + a] - m);
        float accf = 0.f;
        for (int i = start; i < end; i++) {
            float wgt = expf(sex[i*NASP + a] - m) / z;
            accf += wgt * rbuf[((long)i*NASP + a)*256 + t];
        }
        exout[((long)b*NASP + a)*256 + t] = accf;
    }
    {
        float m = -1e30f;
        for (int i = start; i < end; i++) m = fmaxf(m, sim[i]);
        float z = 0.f;
        for (int i = start; i < end; i++) z += expf(sim[i] - m);
        for (int f = t; f < IMD; f += 256) {
            float accf = 0.f;
            for (int i = start; i < end; i++)
                accf += (expf(sim[i] - m) / z) * xbuf[(long)i*IMD + f];
            imout[(long)b*IMD + f] = accf;
        }
    }
}

// ================= K5: final prediction =================
__global__ __launch_bounds__(256) void k5_final(
    const int* __restrict__ uid, const int* __restrict__ iid,
    const float* __restrict__ bu, const float* __restrict__ bt,
    const float* __restrict__ wim2, const float* __restrict__ wex2,
    const float* __restrict__ gamma, float* __restrict__ out)
{
    __shared__ float sb[256];
    int b = blockIdx.x, t = threadIdx.x;
    float p = g_imh[b*256 + t] * wim2[t];
    #pragma unroll
    for (int a = 0; a < NASP; a++)
        p += g_exh[((long)b*NASP + a)*256 + t] * wex2[t] * gamma[a];
    sb[t] = p;
    __syncthreads();
    if (t < 64) {
        float q = sb[t] + sb[t+64] + sb[t+128] + sb[t+192];
        #pragma unroll
        for (int o = 1; o < 64; o <<= 1) q += __shfl_xor(q, o);
        if (t == 0) out[b] = bu[uid[b]] + bt[iid[b]] + q;
    }
}

extern "C" void kernel_launch(void* const* d_in, const int* in_sizes, int n_in,
                              void* d_out, int out_size, void* d_ws, size_t ws_size,
                              hipStream_t stream)
{
    (void)in_sizes; (void)n_in; (void)d_ws; (void)ws_size; (void)out_size;
    const float* u_out_hid = (const float*)d_in[0];
    const float* i_out_hid = (const float*)d_in[1];
    const float* u_pooler  = (const float*)d_in[2];
    const float* i_pooler  = (const float*)d_in[3];
    const float* urevs_loc = (const float*)d_in[4];
    const float* irevs_loc = (const float*)d_in[5];
    const int*   u_seg     = (const int*)d_in[6];
    const int*   i_seg     = (const int*)d_in[7];
    const int*   uid       = (const int*)d_in[8];
    const int*   iid       = (const int*)d_in[9];
    const float* u_emb     = (const float*)d_in[10];
    const float* i_emb     = (const float*)d_in[11];
    const float* W_ub      = (const float*)d_in[12];
    const float* b_ub      = (const float*)d_in[13];
    const float* W_ib      = (const float*)d_in[14];
    const float* b_ib      = (const float*)d_in[15];
    const float* w_exu     = (const float*)d_in[16];
    const float* w_exi     = (const float*)d_in[17];
    const float* w_imu     = (const float*)d_in[18];
    const float* w_imi     = (const float*)d_in[19];
    const float* W_ucls    = (const float*)d_in[20];
    const float* W_icls    = (const float*)d_in[21];
    const float* K_u       = (const float*)d_in[22];
    const float* b_ku      = (const float*)d_in[23];
    const float* K_i       = (const float*)d_in[24];
    const float* b_ki      = (const float*)d_in[25];
    const float* W_ex1     = (const float*)d_in[26];
    const float* b_ex1     = (const float*)d_in[27];
    const float* W_ex2     = (const float*)d_in[28];
    const float* W_im1     = (const float*)d_in[29];
    const float* b_im1     = (const float*)d_in[30];
    const float* W_im2     = (const float*)d_in[31];
    const float* bu_tab    = (const float*)d_in[32];
    const float* bt_tab    = (const float*)d_in[33];
    const float* gamma     = (const float*)d_in[34];
    float* out = (float*)d_out;

    k_prep<<<2773, 256, 0, stream>>>(W_ub, W_ib, K_u, K_i, u_emb, i_emb, w_exu, w_exi);
    k1_gemm<<<4096, 256, 0, stream>>>(0, u_out_hid, b_ub, w_exu);
    k1_gemm<<<4096, 256, 0, stream>>>(1, i_out_hid, b_ib, w_exi);
    k_small_gemm<<<64, 256, 0, stream>>>(0, u_pooler, W_ucls, nullptr, 256, 0);
    k_small_gemm<<<64, 256, 0, stream>>>(1, i_pooler, W_icls, nullptr, 256, 0);
    k2_mega<<<1024, 256, 0, stream>>>(0, b_ku, urevs_loc);
    k2_mega<<<1024, 256, 0, stream>>>(1, b_ki, irevs_loc);
    k3_scores<<<1024, 256, 0, stream>>>(0, urevs_loc, w_imu);
    k3_scores<<<1024, 256, 0, stream>>>(1, irevs_loc, w_imi);
    k4_seg<<<128, 256, 0, stream>>>(0, u_seg);
    k4_seg<<<128, 256, 0, stream>>>(1, i_seg);
    k_small_gemm<<<160, 256, 0, stream>>>(2, nullptr, W_ex1, b_ex1, 256, 256);
    k_small_gemm<<<8, 256, 0, stream>>>(3, nullptr, W_im1, b_im1, IMD, IMD);
    k5_final<<<128, 256, 0, stream>>>(uid, iid, bu_tab, bt_tab, W_im2, W_ex2, gamma, out);
}